// Round 20
// baseline (245.021 us; speedup 1.0000x reference)
//
#include <hip/hip_runtime.h>
#include <hip/hip_bf16.h>
#include <math.h>

typedef __attribute__((ext_vector_type(8))) short short8x;
typedef __attribute__((ext_vector_type(4))) float f32x4;
typedef __attribute__((ext_vector_type(4))) unsigned short u16x4;
typedef __attribute__((ext_vector_type(8))) unsigned short u16x8;

#define NSPLIT 16
#define NTILE 66
#define KVROWS (NTILE * 32)

__device__ __forceinline__ unsigned short f2bf(float x) {
  unsigned int u = __float_as_uint(x);
  u += 0x7fffu + ((u >> 16) & 1u);   // RNE
  return (unsigned short)(u >> 16);
}
__device__ __forceinline__ float bf2f(unsigned short u) {
  return __uint_as_float(((unsigned int)u) << 16);
}
__device__ __forceinline__ u16x4 cvt4(float4 v) {
  u16x4 r;
  r[0] = f2bf(v.x); r[1] = f2bf(v.y); r[2] = f2bf(v.z); r[3] = f2bf(v.w);
  return r;
}
__device__ __forceinline__ void gload_lds16(const void* g, void* l) {
  __builtin_amdgcn_global_load_lds(
      (const __attribute__((address_space(1))) unsigned int*)g,
      (__attribute__((address_space(3))) unsigned int*)l, 16, 0, 0);
}

// ===== k1q: K-split q-proj MFMA, 1536 blocks = 384 row-groups x 4 K-chunks ====
__global__ __launch_bounds__(256, 6) void k1q(
    const float* __restrict__ wq, const float* __restrict__ x,
    float* __restrict__ qpart) {
  const int bx = blockIdx.x;
  const int tid = threadIdx.x;
  const int rowblock = bx >> 2, kq = bx & 3;
  const int lane = tid & 63, wid = tid >> 6;
  const int l15 = lane & 15, lg = lane >> 4;
  const int rowb = rowblock * 64 + wid * 16;
  const float* wrow = wq + (size_t)(rowb + l15) * 1536 + kq * 384 + lg * 8;
  const float* xrow = x + (size_t)l15 * 1536 + kq * 384 + lg * 8;

  f32x4 aHH = (f32x4){0.f, 0.f, 0.f, 0.f};
  f32x4 aHL = (f32x4){0.f, 0.f, 0.f, 0.f};
  f32x4 aLH = (f32x4){0.f, 0.f, 0.f, 0.f};
  f32x4 bHH = (f32x4){0.f, 0.f, 0.f, 0.f};
  f32x4 bHL = (f32x4){0.f, 0.f, 0.f, 0.f};
  f32x4 bLH = (f32x4){0.f, 0.f, 0.f, 0.f};

  float4 wA[2], wB[2], xA[2], xB[2];       // depth-2 rolling prefetch
#pragma unroll
  for (int i = 0; i < 2; ++i) {
    wA[i] = *(const float4*)(wrow + i * 32);
    wB[i] = *(const float4*)(wrow + i * 32 + 4);
    xA[i] = *(const float4*)(xrow + i * 32);
    xB[i] = *(const float4*)(xrow + i * 32 + 4);
  }

#pragma unroll
  for (int kc = 0; kc < 12; ++kc) {        // 12 x 32 floats = 384 K
    const int s = kc & 1;
    const float wf[8] = {wA[s].x, wA[s].y, wA[s].z, wA[s].w,
                         wB[s].x, wB[s].y, wB[s].z, wB[s].w};
    const float xf[8] = {xA[s].x, xA[s].y, xA[s].z, xA[s].w,
                         xB[s].x, xB[s].y, xB[s].z, xB[s].w};
    short8x ah, al, bh, bl;
#pragma unroll
    for (int e = 0; e < 8; ++e) {
      const unsigned int wu = __float_as_uint(wf[e]);
      const float whf = __uint_as_float(wu & 0xffff0000u);
      ah[e] = (short)(wu >> 16);
      al[e] = (short)(__float_as_uint(wf[e] - whf) >> 16);
      const unsigned int xu = __float_as_uint(xf[e]);
      const float xhf = __uint_as_float(xu & 0xffff0000u);
      bh[e] = (short)(xu >> 16);
      bl[e] = (short)(__float_as_uint(xf[e] - xhf) >> 16);
    }
    if (kc + 2 < 12) {
      wA[s] = *(const float4*)(wrow + (kc + 2) * 32);
      wB[s] = *(const float4*)(wrow + (kc + 2) * 32 + 4);
      xA[s] = *(const float4*)(xrow + (kc + 2) * 32);
      xB[s] = *(const float4*)(xrow + (kc + 2) * 32 + 4);
    }
    if (kc & 1) {
      bHH = __builtin_amdgcn_mfma_f32_16x16x32_bf16(ah, bh, bHH, 0, 0, 0);
      bHL = __builtin_amdgcn_mfma_f32_16x16x32_bf16(ah, bl, bHL, 0, 0, 0);
      bLH = __builtin_amdgcn_mfma_f32_16x16x32_bf16(al, bh, bLH, 0, 0, 0);
    } else {
      aHH = __builtin_amdgcn_mfma_f32_16x16x32_bf16(ah, bh, aHH, 0, 0, 0);
      aHL = __builtin_amdgcn_mfma_f32_16x16x32_bf16(ah, bl, aHL, 0, 0, 0);
      aLH = __builtin_amdgcn_mfma_f32_16x16x32_bf16(al, bh, aLH, 0, 0, 0);
    }
  }
  const f32x4 acc = (aHH + bHH) + (aHL + bHL) + (aLH + bLH);
#pragma unroll
  for (int r = 0; r < 4; ++r)
    qpart[(size_t)kq * 393216 + (size_t)l15 * 24576 + rowb + lg * 4 + r] = acc[r];
}

// ===== kPA: KV bf16 stream-convert, 2376 blocks =============================
__global__ __launch_bounds__(256) void kPA(
    const float* __restrict__ ckvc, const float* __restrict__ kpec,
    const float* __restrict__ ckvn, const float* __restrict__ kpein,
    const float* __restrict__ cosc, const float* __restrict__ sinc,
    const int* __restrict__ sposp, int cap,
    unsigned short* __restrict__ kvbf) {
  const int bxx = blockIdx.x;
  const int tid = threadIdx.x;
  const int spos = sposp[0];
#pragma unroll
  for (int i = 0; i < 8; ++i) {
    const int u = bxx * 2048 + i * 256 + tid;      // 4-elem chunk id
    const int b = u / 304128;
    const int r = u - b * 304128;
    const int n = r / 144;
    const int c4 = (r - n * 144) * 4;
    float4 v = make_float4(0.f, 0.f, 0.f, 0.f);
    if (n < spos) {
      if (c4 < 512) v = *(const float4*)(ckvc + ((size_t)b * cap + n) * 512 + c4);
      else          v = *(const float4*)(kpec + ((size_t)b * cap + n) * 64 + (c4 - 512));
    } else if (n == spos) {
      if (c4 < 512) v = *(const float4*)(ckvn + (size_t)b * 512 + c4);
      else {
        const int d = c4 - 512;
        const float* kp = kpein + b * 64;
        float o[4];
        if (d < 32) {
#pragma unroll
          for (int k = 0; k < 4; ++k) {
            int j = d + k;
            o[k] = kp[2 * j] * cosc[spos * 64 + j] - kp[2 * j + 1] * sinc[spos * 64 + j];
          }
        } else {
#pragma unroll
          for (int k = 0; k < 4; ++k) {
            int j = d - 32 + k;
            o[k] = kp[2 * j + 1] * cosc[spos * 64 + j] + kp[2 * j] * sinc[spos * 64 + j];
          }
        }
        v = make_float4(o[0], o[1], o[2], o[3]);
      }
    }
    *(u16x4*)(kvbf + (size_t)u * 4) = cvt4(v);
  }
}

// ===== kB2: absorb (0..255) || rope (256..271) || vT build (272..1327) ========
__global__ __launch_bounds__(256) void kB2(
    const float* __restrict__ qpart, const float* __restrict__ wkv,
    const float* __restrict__ cosc, const float* __restrict__ sinc,
    const int* __restrict__ sposp, unsigned short* __restrict__ qcat,
    const unsigned short* __restrict__ kvbf, unsigned short* __restrict__ vT) {
  __shared__ __align__(16) unsigned char shbuf[36864];
  const int bx = blockIdx.x;
  const int tid = threadIdx.x;

  if (bx < 256) {
    float* qs = (float*)shbuf;   // 16*128 fp32
    const int h = bx & 127;
    const int half = bx >> 7;
    for (int u = tid; u < 2048; u += 256) {
      int bb = u >> 7, d = u & 127;
      const size_t off = (size_t)bb * 24576 + h * 192 + d;
      qs[u] = qpart[off] + qpart[off + 393216] +
              qpart[off + 786432] + qpart[off + 1179648];
    }
    __syncthreads();
    const int c = half * 256 + tid;
    float acc[16];
#pragma unroll
    for (int bb = 0; bb < 16; ++bb) acc[bb] = 0.f;
    const float* wbase = wkv + (size_t)h * 256 * 512;
    for (int d = 0; d < 128; ++d) {
      const float w = wbase[d * 512 + c];
#pragma unroll
      for (int bb = 0; bb < 16; ++bb) acc[bb] += qs[bb * 128 + d] * w;
    }
#pragma unroll
    for (int bb = 0; bb < 16; ++bb)
      qcat[(size_t)(bb * 128 + h) * 576 + c] = f2bf(acc[bb]);
  } else if (bx < 272) {
    const int b = bx - 256;
    const int pos = sposp[0];
#pragma unroll
    for (int i = 0; i < 16; ++i) {
      int idx = tid + i * 256;
      int h = idx >> 5, j = idx & 31;
      const float cj = cosc[pos * 64 + j];
      const float sj = sinc[pos * 64 + j];
      const size_t base = (size_t)b * 24576 + h * 192 + 128;
      float x0 = qpart[base + 2 * j] + qpart[base + 2 * j + 393216] +
                 qpart[base + 2 * j + 786432] + qpart[base + 2 * j + 1179648];
      float x1 = qpart[base + 2 * j + 1] + qpart[base + 2 * j + 1 + 393216] +
                 qpart[base + 2 * j + 1 + 786432] + qpart[base + 2 * j + 1 + 1179648];
      unsigned short* dst = qcat + (size_t)(b * 128 + h) * 576 + 512;
      dst[j] = f2bf(x0 * cj - x1 * sj);
      dst[j + 32] = f2bf(x1 * cj + x0 * sj);
    }
  } else {
    unsigned short* tile_sh = (unsigned short*)shbuf;  // 32*576 u16
    const int v_ = bx - 272;
    const int b = v_ / NTILE;
    const int tile = v_ - b * NTILE;
    const int wid = tid >> 6;
    const unsigned short* src = kvbf + ((size_t)b * KVROWS + tile * 32) * 576;
#pragma unroll
    for (int i = 0; i < 9; ++i) {
      const int ch = i * 256 + tid;          // 16B chunk 0..2303
      const int row = ch / 72, cc = ch - row * 72;
      gload_lds16(src + row * 576 + ((cc ^ (row & 7)) * 8),
                  &tile_sh[(i * 256 + wid * 64) * 8]);
    }
    __syncthreads();
    unsigned short* vdst = vT + ((size_t)b * NTILE + tile) * 18432;
#pragma unroll
    for (int r = 0; r < 9; ++r) {
      const int c = r * 64 + (tid >> 2);     // column 0..575
      const int q = tid & 3;                 // n-oct
      const int c8 = c >> 3, c7 = c & 7;
      u16x8 w;
#pragma unroll
      for (int j = 0; j < 8; ++j)            // element (n=q*8+j, c); n&7 == j
        w[j] = tile_sh[(q * 8 + j) * 576 + ((c8 ^ j) << 3) + c7];
      *(u16x8*)(vdst + c * 32 + q * 8) = w;
    }
  }
}

// ===== k4: flash decode, 8 waves = 128 heads, dbuf gload_lds ==================
__global__ __launch_bounds__(512, 2) void k4_attn(
    const unsigned short* __restrict__ kvbf, const unsigned short* __restrict__ vT,
    const unsigned short* __restrict__ qcat, const int* __restrict__ sposp,
    unsigned short* __restrict__ opart, float* __restrict__ mlp) {
  __shared__ __align__(16) unsigned short kv_sh[2][32 * 576];
  __shared__ __align__(16) unsigned short vt_sh[2][512 * 32];
  __shared__ __align__(16) unsigned short p_sh[8 * 640];

  const int tid = threadIdx.x;
  const int split = blockIdx.x, b = blockIdx.y;
  const int kvlen = sposp[0] + 1;
  const int lane = tid & 63, wid = tid >> 6;
  const int l15 = lane & 15, lg = lane >> 4;

  const unsigned short* kvb = kvbf + (size_t)b * KVROWS * 576;
  const unsigned short* vtb = vT + (size_t)b * NTILE * 18432;

  const int vro = lane >> 2, vq = lane & 3;
  const int vgq = vq ^ ((vro >> 1) & 3);

  auto STAGE = [&](int pb, int tt) {
    const unsigned short* ksrc = kvb + (size_t)tt * 32 * 576;
    for (int j = wid; j < 36; j += 8) {
      int u = j * 64 + lane;
      int row = u / 72, cc = u - row * 72;
      gload_lds16(ksrc + row * 576 + ((cc ^ (row & 7)) * 8), &kv_sh[pb][j * 512]);
    }
    const unsigned short* vsrc = vtb + (size_t)tt * 18432;
    for (int j = wid; j < 32; j += 8)
      gload_lds16(vsrc + j * 512 + vro * 32 + vgq * 8, &vt_sh[pb][j * 512]);
  };

  STAGE(0, split);

  const int hrow = b * 128 + wid * 16 + l15;
  const unsigned short* qrow = qcat + (size_t)hrow * 576;
  short8x qf[18];
#pragma unroll
  for (int s = 0; s < 18; ++s)
    qf[s] = *(const short8x*)(qrow + s * 32 + lg * 8);

  f32x4 acc[32];
#pragma unroll
  for (int i = 0; i < 32; ++i) acc[i] = (f32x4){0.f, 0.f, 0.f, 0.f};
  float mold[4] = {-1e30f, -1e30f, -1e30f, -1e30f};
  float lsum[4] = {0.f, 0.f, 0.f, 0.f};
  const float C2 = (1.0f / sqrtf(192.0f)) * 1.4426950408889634f;

  const int vrd = ((lg ^ ((l15 >> 1) & 3)) << 3);  // swizzled PV read chunk

  int pb = 0;
  for (int tt = split; tt * 32 < kvlen; tt += NSPLIT, pb ^= 1) {
    __syncthreads();
    if ((tt + NSPLIT) * 32 < kvlen) STAGE(pb ^ 1, tt + NSPLIT);
    const int n0 = tt * 32;

    f32x4 D0 = (f32x4){0.f, 0.f, 0.f, 0.f};
    f32x4 D1 = (f32x4){0.f, 0.f, 0.f, 0.f};
#pragma unroll
    for (int s = 0; s < 18; ++s) {
      const int c8 = (s * 4 + lg) ^ (l15 & 7);
      short8x fb0 = *(const short8x*)&kv_sh[pb][l15 * 576 + c8 * 8];
      short8x fb1 = *(const short8x*)&kv_sh[pb][(16 + l15) * 576 + c8 * 8];
      D0 = __builtin_amdgcn_mfma_f32_16x16x32_bf16(qf[s], fb0, D0, 0, 0, 0);
      D1 = __builtin_amdgcn_mfma_f32_16x16x32_bf16(qf[s], fb1, D1, 0, 0, 0);
    }

    const bool v0 = (n0 + l15) < kvlen;
    const bool v1 = (n0 + 16 + l15) < kvlen;
    float alpha[4];
#pragma unroll
    for (int r = 0; r < 4; ++r) {
      const float t0 = v0 ? D0[r] * C2 : -1e30f;
      const float t1 = v1 ? D1[r] * C2 : -1e30f;
      float mx = fmaxf(t0, t1);
      mx = fmaxf(mx, __shfl_xor(mx, 1, 64));
      mx = fmaxf(mx, __shfl_xor(mx, 2, 64));
      mx = fmaxf(mx, __shfl_xor(mx, 4, 64));
      mx = fmaxf(mx, __shfl_xor(mx, 8, 64));
      const float mn = fmaxf(mold[r], mx);
      alpha[r] = exp2f(mold[r] - mn);
      const float p0 = v0 ? exp2f(t0 - mn) : 0.f;
      const float p1 = v1 ? exp2f(t1 - mn) : 0.f;
      float rs = p0 + p1;
      rs += __shfl_xor(rs, 1, 64);
      rs += __shfl_xor(rs, 2, 64);
      rs += __shfl_xor(rs, 4, 64);
      rs += __shfl_xor(rs, 8, 64);
      lsum[r] = lsum[r] * alpha[r] + rs;
      mold[r] = mn;
      p_sh[wid * 640 + (lg * 4 + r) * 40 + l15] = f2bf(p0);
      p_sh[wid * 640 + (lg * 4 + r) * 40 + 16 + l15] = f2bf(p1);
    }
    const f32x4 av = {alpha[0], alpha[1], alpha[2], alpha[3]};
#pragma unroll
    for (int cg = 0; cg < 32; ++cg) acc[cg] *= av;

    const short8x pa = *(const short8x*)&p_sh[wid * 640 + l15 * 40 + lg * 8];
#pragma unroll
    for (int cg = 0; cg < 32; ++cg) {
      short8x bv = *(const short8x*)&vt_sh[pb][cg * 512 + l15 * 32 + vrd];
      acc[cg] = __builtin_amdgcn_mfma_f32_16x16x32_bf16(pa, bv, acc[cg], 0, 0, 0);
    }
  }

  const int hbm_ = b * 128 + wid * 16 + lg * 4;
  if (l15 == 0) {
#pragma unroll
    for (int r = 0; r < 4; ++r) {
      mlp[(size_t)(hbm_ + r) * (2 * NSPLIT) + split * 2] = mold[r];
      mlp[(size_t)(hbm_ + r) * (2 * NSPLIT) + split * 2 + 1] = lsum[r];
    }
  }

  __syncthreads();
  unsigned short* ep = &kv_sh[0][0] + wid * 8192;
#pragma unroll
  for (int cg = 0; cg < 32; ++cg)
#pragma unroll
    for (int r = 0; r < 4; ++r)
      ep[(lg * 4 + r) * 512 + cg * 16 + l15] = f2bf(acc[cg][r]);
#pragma unroll
  for (int r16 = 0; r16 < 16; ++r16) {
    const int bh = b * 128 + wid * 16 + r16;
    const size_t ob = ((size_t)bh * NSPLIT + split) * 512;
#pragma unroll
    for (int i = 0; i < 2; ++i)
      *(u16x4*)&opart[ob + i * 256 + lane * 4] =
          *(const u16x4*)&ep[r16 * 512 + i * 256 + lane * 4];
  }
}

// ===== kC: fused combine + V-proj (one block per head) ========================
__global__ __launch_bounds__(512) void kC_out(
    const unsigned short* __restrict__ opart, const float* __restrict__ mlp,
    const float* __restrict__ wkv, float* __restrict__ out) {
  __shared__ float os[16 * 512];
  __shared__ float wsc[16 * 16];
  __shared__ float lsc[16];
  const int h = blockIdx.x;
  const int tid = threadIdx.x;

  if (tid < 16) {
    const int b = tid;
    const float* m = mlp + (size_t)(b * 128 + h) * (2 * NSPLIT);
    float mi[NSPLIT], li[NSPLIT], M = -1e30f;
#pragma unroll
    for (int i = 0; i < NSPLIT; ++i) {
      mi[i] = m[i * 2];
      li[i] = m[i * 2 + 1];
      M = fmaxf(M, mi[i]);
    }
    float Ls = 0.f;
#pragma unroll
    for (int i = 0; i < NSPLIT; ++i) {
      const float w = exp2f(mi[i] - M);
      Ls += li[i] * w;
      wsc[b * NSPLIT + i] = w;
    }
    lsc[b] = Ls;
  }
  __syncthreads();

  for (int u = tid; u < 8192; u += 512) {
    const int b = u >> 9, c = u & 511;
    const unsigned short* op = opart + (size_t)(b * 128 + h) * NSPLIT * 512 + c;
    float o = 0.f;
#pragma unroll
    for (int i = 0; i < NSPLIT; ++i) o += wsc[b * NSPLIT + i] * bf2f(op[i * 512]);
    os[u] = o / lsc[b];
  }
  __syncthreads();

  const int d = tid >> 2, cq = tid & 3;
  const float* wrow = wkv + ((size_t)(h * 256 + 128 + d)) * 512;
  float acc[16];
#pragma unroll
  for (int bb = 0; bb < 16; ++bb) acc[bb] = 0.f;
  for (int i = 0; i < 32; ++i) {
    const int c = cq * 4 + i * 16;
    const float4 w4 = *(const float4*)&wrow[c];
#pragma unroll
    for (int bb = 0; bb < 16; ++bb) {
      const float4 o4 = *(const float4*)&os[bb * 512 + c];
      acc[bb] += w4.x * o4.x + w4.y * o4.y + w4.z * o4.z + w4.w * o4.w;
    }
  }
#pragma unroll
  for (int bb = 0; bb < 16; ++bb) {
    float v = acc[bb];
    v += __shfl_xor(v, 1, 64);
    v += __shfl_xor(v, 2, 64);
    if (cq == 0) out[(size_t)(bb * 128 + h) * 128 + d] = v;
  }
}

extern "C" void kernel_launch(void* const* d_in, const int* in_sizes, int n_in,
                              void* d_out, int out_size, void* d_ws, size_t ws_size,
                              hipStream_t stream) {
  const float* x = (const float*)d_in[0];
  const float* ckvn = (const float*)d_in[1];
  const float* kpein = (const float*)d_in[2];
  const int* sposp = (const int*)d_in[4];
  const float* ckvc = (const float*)d_in[5];
  const float* kpec = (const float*)d_in[6];
  const float* sinc = (const float*)d_in[7];
  const float* cosc = (const float*)d_in[8];
  const float* wkv = (const float*)d_in[9];
  const float* wq = (const float*)d_in[10];
  float* out = (float*)d_out;

  const int cap = in_sizes[5] / (16 * 512);

  float* ws = (float*)d_ws;
  float* qpart = ws;                                        // 4 x 393,216 f
  float* mlp = ws + 1572864;                                // 65,536 f
  unsigned short* qcat = (unsigned short*)(ws + 1638400);   // 1,179,648 u16
  unsigned short* kvbf = (unsigned short*)(ws + 2228224);   // 19,464,192 u16
  unsigned short* vT   = (unsigned short*)(ws + 11960320);  // 19,464,192 u16
  unsigned short* opart = (unsigned short*)(ws + 21692416); // 16,777,216 u16

  // MEASUREMENT ROUND: k1q launched 3x (idempotent); T(k1q) = (dur - 178.4)/2
  k1q<<<dim3(1536), 256, 0, stream>>>(wq, x, qpart);
  k1q<<<dim3(1536), 256, 0, stream>>>(wq, x, qpart);
  k1q<<<dim3(1536), 256, 0, stream>>>(wq, x, qpart);
  kPA<<<dim3(2376), 256, 0, stream>>>(ckvc, kpec, ckvn, kpein, cosc, sinc,
                                      sposp, cap, kvbf);
  kB2<<<dim3(272 + NTILE * 16), 256, 0, stream>>>(qpart, wkv, cosc, sinc, sposp,
                                                  qcat, kvbf, vT);
  k4_attn<<<dim3(NSPLIT, 16), 512, 0, stream>>>(kvbf, vT, qcat, sposp, opart, mlp);
  kC_out<<<dim3(128), 512, 0, stream>>>(opart, mlp, wkv, out);
}

// Round 21
// 164.252 us; speedup vs baseline: 1.4917x; 1.4917x over previous
//
#include <hip/hip_runtime.h>
#include <hip/hip_bf16.h>
#include <math.h>

typedef __attribute__((ext_vector_type(8))) short short8x;
typedef __attribute__((ext_vector_type(4))) float f32x4;
typedef __attribute__((ext_vector_type(4))) unsigned short u16x4;
typedef __attribute__((ext_vector_type(8))) unsigned short u16x8;

#define NSPLIT 16
#define NTILE 66
#define KVROWS (NTILE * 32)

__device__ __forceinline__ unsigned short f2bf(float x) {
  unsigned int u = __float_as_uint(x);
  u += 0x7fffu + ((u >> 16) & 1u);   // RNE
  return (unsigned short)(u >> 16);
}
__device__ __forceinline__ float bf2f(unsigned short u) {
  return __uint_as_float(((unsigned int)u) << 16);
}
__device__ __forceinline__ u16x4 cvt4(float4 v) {
  u16x4 r;
  r[0] = f2bf(v.x); r[1] = f2bf(v.y); r[2] = f2bf(v.z); r[3] = f2bf(v.w);
  return r;
}
__device__ __forceinline__ void gload_lds16(const void* g, void* l) {
  __builtin_amdgcn_global_load_lds(
      (const __attribute__((address_space(1))) unsigned int*)g,
      (__attribute__((address_space(3))) unsigned int*)l, 16, 0, 0);
}

// ===== kA: K-split q-proj MFMA (0..1535) || KV convert v2 (1536..3911) ========
// kPA v2: 16-elem granules, all loads hoisted before stores, 16B stores.
__global__ __launch_bounds__(256, 4) void kA(
    const float* __restrict__ ckvc, const float* __restrict__ kpec,
    const float* __restrict__ ckvn, const float* __restrict__ kpein,
    const float* __restrict__ cosc, const float* __restrict__ sinc,
    const int* __restrict__ sposp, int cap,
    unsigned short* __restrict__ kvbf,
    const float* __restrict__ wq, const float* __restrict__ x,
    float* __restrict__ qpart) {
  const int bx = blockIdx.x;
  const int tid = threadIdx.x;

  if (bx < 1536) {
    const int rowblock = bx >> 2, kq = bx & 3;
    const int lane = tid & 63, wid = tid >> 6;
    const int l15 = lane & 15, lg = lane >> 4;
    const int rowb = rowblock * 64 + wid * 16;
    const float* wrow = wq + (size_t)(rowb + l15) * 1536 + kq * 384 + lg * 8;
    const float* xrow = x + (size_t)l15 * 1536 + kq * 384 + lg * 8;

    f32x4 aHH = (f32x4){0.f, 0.f, 0.f, 0.f};
    f32x4 aHL = (f32x4){0.f, 0.f, 0.f, 0.f};
    f32x4 aLH = (f32x4){0.f, 0.f, 0.f, 0.f};
    f32x4 bHH = (f32x4){0.f, 0.f, 0.f, 0.f};
    f32x4 bHL = (f32x4){0.f, 0.f, 0.f, 0.f};
    f32x4 bLH = (f32x4){0.f, 0.f, 0.f, 0.f};

    float4 wA[2], wB[2], xA[2], xB[2];
#pragma unroll
    for (int i = 0; i < 2; ++i) {
      wA[i] = *(const float4*)(wrow + i * 32);
      wB[i] = *(const float4*)(wrow + i * 32 + 4);
      xA[i] = *(const float4*)(xrow + i * 32);
      xB[i] = *(const float4*)(xrow + i * 32 + 4);
    }

#pragma unroll
    for (int kc = 0; kc < 12; ++kc) {
      const int s = kc & 1;
      const float wf[8] = {wA[s].x, wA[s].y, wA[s].z, wA[s].w,
                           wB[s].x, wB[s].y, wB[s].z, wB[s].w};
      const float xf[8] = {xA[s].x, xA[s].y, xA[s].z, xA[s].w,
                           xB[s].x, xB[s].y, xB[s].z, xB[s].w};
      short8x ah, al, bh, bl;
#pragma unroll
      for (int e = 0; e < 8; ++e) {
        const unsigned int wu = __float_as_uint(wf[e]);
        const float whf = __uint_as_float(wu & 0xffff0000u);
        ah[e] = (short)(wu >> 16);
        al[e] = (short)(__float_as_uint(wf[e] - whf) >> 16);
        const unsigned int xu = __float_as_uint(xf[e]);
        const float xhf = __uint_as_float(xu & 0xffff0000u);
        bh[e] = (short)(xu >> 16);
        bl[e] = (short)(__float_as_uint(xf[e] - xhf) >> 16);
      }
      if (kc + 2 < 12) {
        wA[s] = *(const float4*)(wrow + (kc + 2) * 32);
        wB[s] = *(const float4*)(wrow + (kc + 2) * 32 + 4);
        xA[s] = *(const float4*)(xrow + (kc + 2) * 32);
        xB[s] = *(const float4*)(xrow + (kc + 2) * 32 + 4);
      }
      if (kc & 1) {
        bHH = __builtin_amdgcn_mfma_f32_16x16x32_bf16(ah, bh, bHH, 0, 0, 0);
        bHL = __builtin_amdgcn_mfma_f32_16x16x32_bf16(ah, bl, bHL, 0, 0, 0);
        bLH = __builtin_amdgcn_mfma_f32_16x16x32_bf16(al, bh, bLH, 0, 0, 0);
      } else {
        aHH = __builtin_amdgcn_mfma_f32_16x16x32_bf16(ah, bh, aHH, 0, 0, 0);
        aHL = __builtin_amdgcn_mfma_f32_16x16x32_bf16(ah, bl, aHL, 0, 0, 0);
        aLH = __builtin_amdgcn_mfma_f32_16x16x32_bf16(al, bh, aLH, 0, 0, 0);
      }
    }
    const f32x4 acc = (aHH + bHH) + (aHL + bHL) + (aLH + bLH);
#pragma unroll
    for (int r = 0; r < 4; ++r)
      qpart[(size_t)kq * 393216 + (size_t)l15 * 24576 + rowb + lg * 4 + r] = acc[r];
  } else {
    // ---- kPA v2: 4 granules/thread; phase1 = 8 hoisted float4 loads ----
    const int bxx = bx - 1536;
    const int spos = sposp[0];
    float4 va[4], vb[4];
    int nn[4], cc[4], bg[4];
#pragma unroll
    for (int g = 0; g < 4; ++g) {
      const int u = bxx * 1024 + g * 256 + tid;     // u16x8 granule id
      const int b = u / 152064;                     // 2112 rows * 72 granules
      const int r = u - b * 152064;
      const int n = r / 72;
      const int c8 = (r - n * 72) * 8;
      bg[g] = b; nn[g] = n; cc[g] = c8;
      const float* s0;
      if (n < spos) {
        s0 = (c8 < 512) ? ckvc + ((size_t)b * cap + n) * 512 + c8
                        : kpec + ((size_t)b * cap + n) * 64 + (c8 - 512);
      } else if (n == spos && c8 < 512) {
        s0 = ckvn + (size_t)b * 512 + c8;
      } else {
        s0 = ckvc;                                  // dummy safe read
      }
      va[g] = *(const float4*)s0;
      vb[g] = *(const float4*)(s0 + 4);
    }
#pragma unroll
    for (int g = 0; g < 4; ++g) {
      const int u = bxx * 1024 + g * 256 + tid;
      const int n = nn[g], c8 = cc[g], b = bg[g];
      u16x8 w;
      if (n > spos) {
#pragma unroll
        for (int k = 0; k < 8; ++k) w[k] = 0;
      } else if (n == spos && c8 >= 512) {
        const int d = c8 - 512;
        const float* kp = kpein + b * 64;
#pragma unroll
        for (int k = 0; k < 8; ++k) {
          const int dd = d + k;
          const int j = (dd < 32) ? dd : dd - 32;
          const float cj = cosc[spos * 64 + j], sj = sinc[spos * 64 + j];
          const float val = (dd < 32) ? kp[2 * j] * cj - kp[2 * j + 1] * sj
                                      : kp[2 * j + 1] * cj + kp[2 * j] * sj;
          w[k] = f2bf(val);
        }
      } else {
        const u16x4 lo = cvt4(va[g]), hi = cvt4(vb[g]);
#pragma unroll
        for (int k = 0; k < 4; ++k) { w[k] = lo[k]; w[4 + k] = hi[k]; }
      }
      *(u16x8*)(kvbf + (size_t)u * 8) = w;
    }
  }
}

// ===== kB2: absorb (0..255) || rope (256..271) || vT build (272..1327) ========
__global__ __launch_bounds__(256) void kB2(
    const float* __restrict__ qpart, const float* __restrict__ wkv,
    const float* __restrict__ cosc, const float* __restrict__ sinc,
    const int* __restrict__ sposp, unsigned short* __restrict__ qcat,
    const unsigned short* __restrict__ kvbf, unsigned short* __restrict__ vT) {
  __shared__ __align__(16) unsigned char shbuf[36864];
  const int bx = blockIdx.x;
  const int tid = threadIdx.x;

  if (bx < 256) {
    float* qs = (float*)shbuf;   // 16*128 fp32
    const int h = bx & 127;
    const int half = bx >> 7;
    for (int u = tid; u < 2048; u += 256) {
      int bb = u >> 7, d = u & 127;
      const size_t off = (size_t)bb * 24576 + h * 192 + d;
      qs[u] = qpart[off] + qpart[off + 393216] +
              qpart[off + 786432] + qpart[off + 1179648];
    }
    __syncthreads();
    const int c = half * 256 + tid;
    float acc[16];
#pragma unroll
    for (int bb = 0; bb < 16; ++bb) acc[bb] = 0.f;
    const float* wbase = wkv + (size_t)h * 256 * 512;
    for (int d = 0; d < 128; ++d) {
      const float w = wbase[d * 512 + c];
#pragma unroll
      for (int bb = 0; bb < 16; ++bb) acc[bb] += qs[bb * 128 + d] * w;
    }
#pragma unroll
    for (int bb = 0; bb < 16; ++bb)
      qcat[(size_t)(bb * 128 + h) * 576 + c] = f2bf(acc[bb]);
  } else if (bx < 272) {
    const int b = bx - 256;
    const int pos = sposp[0];
#pragma unroll
    for (int i = 0; i < 16; ++i) {
      int idx = tid + i * 256;
      int h = idx >> 5, j = idx & 31;
      const float cj = cosc[pos * 64 + j];
      const float sj = sinc[pos * 64 + j];
      const size_t base = (size_t)b * 24576 + h * 192 + 128;
      float x0 = qpart[base + 2 * j] + qpart[base + 2 * j + 393216] +
                 qpart[base + 2 * j + 786432] + qpart[base + 2 * j + 1179648];
      float x1 = qpart[base + 2 * j + 1] + qpart[base + 2 * j + 1 + 393216] +
                 qpart[base + 2 * j + 1 + 786432] + qpart[base + 2 * j + 1 + 1179648];
      unsigned short* dst = qcat + (size_t)(b * 128 + h) * 576 + 512;
      dst[j] = f2bf(x0 * cj - x1 * sj);
      dst[j + 32] = f2bf(x1 * cj + x0 * sj);
    }
  } else {
    unsigned short* tile_sh = (unsigned short*)shbuf;  // 32*576 u16
    const int v_ = bx - 272;
    const int b = v_ / NTILE;
    const int tile = v_ - b * NTILE;
    const int wid = tid >> 6;
    const unsigned short* src = kvbf + ((size_t)b * KVROWS + tile * 32) * 576;
#pragma unroll
    for (int i = 0; i < 9; ++i) {
      const int ch = i * 256 + tid;          // 16B chunk 0..2303
      const int row = ch / 72, cc = ch - row * 72;
      gload_lds16(src + row * 576 + ((cc ^ (row & 7)) * 8),
                  &tile_sh[(i * 256 + wid * 64) * 8]);
    }
    __syncthreads();
    unsigned short* vdst = vT + ((size_t)b * NTILE + tile) * 18432;
#pragma unroll
    for (int r = 0; r < 9; ++r) {
      const int c = r * 64 + (tid >> 2);     // column 0..575
      const int q = tid & 3;                 // n-oct
      const int c8 = c >> 3, c7 = c & 7;
      u16x8 w;
#pragma unroll
      for (int j = 0; j < 8; ++j)            // element (n=q*8+j, c); n&7 == j
        w[j] = tile_sh[(q * 8 + j) * 576 + ((c8 ^ j) << 3) + c7];
      *(u16x8*)(vdst + c * 32 + q * 8) = w;
    }
  }
}

// ===== k4: flash decode, 8 waves = 128 heads, dbuf gload_lds ==================
__global__ __launch_bounds__(512, 2) void k4_attn(
    const unsigned short* __restrict__ kvbf, const unsigned short* __restrict__ vT,
    const unsigned short* __restrict__ qcat, const int* __restrict__ sposp,
    unsigned short* __restrict__ opart, float* __restrict__ mlp) {
  __shared__ __align__(16) unsigned short kv_sh[2][32 * 576];
  __shared__ __align__(16) unsigned short vt_sh[2][512 * 32];
  __shared__ __align__(16) unsigned short p_sh[8 * 640];

  const int tid = threadIdx.x;
  const int split = blockIdx.x, b = blockIdx.y;
  const int kvlen = sposp[0] + 1;
  const int lane = tid & 63, wid = tid >> 6;
  const int l15 = lane & 15, lg = lane >> 4;

  const unsigned short* kvb = kvbf + (size_t)b * KVROWS * 576;
  const unsigned short* vtb = vT + (size_t)b * NTILE * 18432;

  const int vro = lane >> 2, vq = lane & 3;
  const int vgq = vq ^ ((vro >> 1) & 3);

  auto STAGE = [&](int pb, int tt) {
    const unsigned short* ksrc = kvb + (size_t)tt * 32 * 576;
    for (int j = wid; j < 36; j += 8) {
      int u = j * 64 + lane;
      int row = u / 72, cc = u - row * 72;
      gload_lds16(ksrc + row * 576 + ((cc ^ (row & 7)) * 8), &kv_sh[pb][j * 512]);
    }
    const unsigned short* vsrc = vtb + (size_t)tt * 18432;
    for (int j = wid; j < 32; j += 8)
      gload_lds16(vsrc + j * 512 + vro * 32 + vgq * 8, &vt_sh[pb][j * 512]);
  };

  STAGE(0, split);

  const int hrow = b * 128 + wid * 16 + l15;
  const unsigned short* qrow = qcat + (size_t)hrow * 576;
  short8x qf[18];
#pragma unroll
  for (int s = 0; s < 18; ++s)
    qf[s] = *(const short8x*)(qrow + s * 32 + lg * 8);

  f32x4 acc[32];
#pragma unroll
  for (int i = 0; i < 32; ++i) acc[i] = (f32x4){0.f, 0.f, 0.f, 0.f};
  float mold[4] = {-1e30f, -1e30f, -1e30f, -1e30f};
  float lsum[4] = {0.f, 0.f, 0.f, 0.f};
  const float C2 = (1.0f / sqrtf(192.0f)) * 1.4426950408889634f;

  const int vrd = ((lg ^ ((l15 >> 1) & 3)) << 3);  // swizzled PV read chunk

  int pb = 0;
  for (int tt = split; tt * 32 < kvlen; tt += NSPLIT, pb ^= 1) {
    __syncthreads();
    if ((tt + NSPLIT) * 32 < kvlen) STAGE(pb ^ 1, tt + NSPLIT);
    const int n0 = tt * 32;

    f32x4 D0 = (f32x4){0.f, 0.f, 0.f, 0.f};
    f32x4 D1 = (f32x4){0.f, 0.f, 0.f, 0.f};
#pragma unroll
    for (int s = 0; s < 18; ++s) {
      const int c8 = (s * 4 + lg) ^ (l15 & 7);
      short8x fb0 = *(const short8x*)&kv_sh[pb][l15 * 576 + c8 * 8];
      short8x fb1 = *(const short8x*)&kv_sh[pb][(16 + l15) * 576 + c8 * 8];
      D0 = __builtin_amdgcn_mfma_f32_16x16x32_bf16(qf[s], fb0, D0, 0, 0, 0);
      D1 = __builtin_amdgcn_mfma_f32_16x16x32_bf16(qf[s], fb1, D1, 0, 0, 0);
    }

    const bool v0 = (n0 + l15) < kvlen;
    const bool v1 = (n0 + 16 + l15) < kvlen;
    float alpha[4];
#pragma unroll
    for (int r = 0; r < 4; ++r) {
      const float t0 = v0 ? D0[r] * C2 : -1e30f;
      const float t1 = v1 ? D1[r] * C2 : -1e30f;
      float mx = fmaxf(t0, t1);
      mx = fmaxf(mx, __shfl_xor(mx, 1, 64));
      mx = fmaxf(mx, __shfl_xor(mx, 2, 64));
      mx = fmaxf(mx, __shfl_xor(mx, 4, 64));
      mx = fmaxf(mx, __shfl_xor(mx, 8, 64));
      const float mn = fmaxf(mold[r], mx);
      alpha[r] = exp2f(mold[r] - mn);
      const float p0 = v0 ? exp2f(t0 - mn) : 0.f;
      const float p1 = v1 ? exp2f(t1 - mn) : 0.f;
      float rs = p0 + p1;
      rs += __shfl_xor(rs, 1, 64);
      rs += __shfl_xor(rs, 2, 64);
      rs += __shfl_xor(rs, 4, 64);
      rs += __shfl_xor(rs, 8, 64);
      lsum[r] = lsum[r] * alpha[r] + rs;
      mold[r] = mn;
      p_sh[wid * 640 + (lg * 4 + r) * 40 + l15] = f2bf(p0);
      p_sh[wid * 640 + (lg * 4 + r) * 40 + 16 + l15] = f2bf(p1);
    }
    const f32x4 av = {alpha[0], alpha[1], alpha[2], alpha[3]};
#pragma unroll
    for (int cg = 0; cg < 32; ++cg) acc[cg] *= av;

    const short8x pa = *(const short8x*)&p_sh[wid * 640 + l15 * 40 + lg * 8];
#pragma unroll
    for (int cg = 0; cg < 32; ++cg) {
      short8x bv = *(const short8x*)&vt_sh[pb][cg * 512 + l15 * 32 + vrd];
      acc[cg] = __builtin_amdgcn_mfma_f32_16x16x32_bf16(pa, bv, acc[cg], 0, 0, 0);
    }
  }

  const int hbm_ = b * 128 + wid * 16 + lg * 4;
  if (l15 == 0) {
#pragma unroll
    for (int r = 0; r < 4; ++r) {
      mlp[(size_t)(hbm_ + r) * (2 * NSPLIT) + split * 2] = mold[r];
      mlp[(size_t)(hbm_ + r) * (2 * NSPLIT) + split * 2 + 1] = lsum[r];
    }
  }

  __syncthreads();
  unsigned short* ep = &kv_sh[0][0] + wid * 8192;
#pragma unroll
  for (int cg = 0; cg < 32; ++cg)
#pragma unroll
    for (int r = 0; r < 4; ++r)
      ep[(lg * 4 + r) * 512 + cg * 16 + l15] = f2bf(acc[cg][r]);
#pragma unroll
  for (int r16 = 0; r16 < 16; ++r16) {
    const int bh = b * 128 + wid * 16 + r16;
    const size_t ob = ((size_t)bh * NSPLIT + split) * 512;
#pragma unroll
    for (int i = 0; i < 2; ++i)
      *(u16x4*)&opart[ob + i * 256 + lane * 4] =
          *(const u16x4*)&ep[r16 * 512 + i * 256 + lane * 4];
  }
}

// ===== kC: fused combine + V-proj (one block per head) ========================
__global__ __launch_bounds__(512) void kC_out(
    const unsigned short* __restrict__ opart, const float* __restrict__ mlp,
    const float* __restrict__ wkv, float* __restrict__ out) {
  __shared__ float os[16 * 512];
  __shared__ float wsc[16 * 16];
  __shared__ float lsc[16];
  const int h = blockIdx.x;
  const int tid = threadIdx.x;

  if (tid < 16) {
    const int b = tid;
    const float* m = mlp + (size_t)(b * 128 + h) * (2 * NSPLIT);
    float mi[NSPLIT], li[NSPLIT], M = -1e30f;
#pragma unroll
    for (int i = 0; i < NSPLIT; ++i) {
      mi[i] = m[i * 2];
      li[i] = m[i * 2 + 1];
      M = fmaxf(M, mi[i]);
    }
    float Ls = 0.f;
#pragma unroll
    for (int i = 0; i < NSPLIT; ++i) {
      const float w = exp2f(mi[i] - M);
      Ls += li[i] * w;
      wsc[b * NSPLIT + i] = w;
    }
    lsc[b] = Ls;
  }
  __syncthreads();

  for (int u = tid; u < 8192; u += 512) {
    const int b = u >> 9, c = u & 511;
    const unsigned short* op = opart + (size_t)(b * 128 + h) * NSPLIT * 512 + c;
    float o = 0.f;
#pragma unroll
    for (int i = 0; i < NSPLIT; ++i) o += wsc[b * NSPLIT + i] * bf2f(op[i * 512]);
    os[u] = o / lsc[b];
  }
  __syncthreads();

  const int d = tid >> 2, cq = tid & 3;
  const float* wrow = wkv + ((size_t)(h * 256 + 128 + d)) * 512;
  float acc[16];
#pragma unroll
  for (int bb = 0; bb < 16; ++bb) acc[bb] = 0.f;
  for (int i = 0; i < 32; ++i) {
    const int c = cq * 4 + i * 16;
    const float4 w4 = *(const float4*)&wrow[c];
#pragma unroll
    for (int bb = 0; bb < 16; ++bb) {
      const float4 o4 = *(const float4*)&os[bb * 512 + c];
      acc[bb] += w4.x * o4.x + w4.y * o4.y + w4.z * o4.z + w4.w * o4.w;
    }
  }
#pragma unroll
  for (int bb = 0; bb < 16; ++bb) {
    float v = acc[bb];
    v += __shfl_xor(v, 1, 64);
    v += __shfl_xor(v, 2, 64);
    if (cq == 0) out[(size_t)(bb * 128 + h) * 128 + d] = v;
  }
}

extern "C" void kernel_launch(void* const* d_in, const int* in_sizes, int n_in,
                              void* d_out, int out_size, void* d_ws, size_t ws_size,
                              hipStream_t stream) {
  const float* x = (const float*)d_in[0];
  const float* ckvn = (const float*)d_in[1];
  const float* kpein = (const float*)d_in[2];
  const int* sposp = (const int*)d_in[4];
  const float* ckvc = (const float*)d_in[5];
  const float* kpec = (const float*)d_in[6];
  const float* sinc = (const float*)d_in[7];
  const float* cosc = (const float*)d_in[8];
  const float* wkv = (const float*)d_in[9];
  const float* wq = (const float*)d_in[10];
  float* out = (float*)d_out;

  const int cap = in_sizes[5] / (16 * 512);

  float* ws = (float*)d_ws;
  float* qpart = ws;                                        // 4 x 393,216 f
  float* mlp = ws + 1572864;                                // 65,536 f
  unsigned short* qcat = (unsigned short*)(ws + 1638400);   // 1,179,648 u16
  unsigned short* kvbf = (unsigned short*)(ws + 2228224);   // 19,464,192 u16
  unsigned short* vT   = (unsigned short*)(ws + 11960320);  // 19,464,192 u16
  unsigned short* opart = (unsigned short*)(ws + 21692416); // 16,777,216 u16

  kA<<<dim3(1536 + 2376), 256, 0, stream>>>(ckvc, kpec, ckvn, kpein, cosc, sinc,
                                            sposp, cap, kvbf, wq, x, qpart);
  kB2<<<dim3(272 + NTILE * 16), 256, 0, stream>>>(qpart, wkv, cosc, sinc, sposp,
                                                  qcat, kvbf, vT);
  k4_attn<<<dim3(NSPLIT, 16), 512, 0, stream>>>(kvbf, vT, qcat, sposp, opart, mlp);
  kC_out<<<dim3(128), 512, 0, stream>>>(opart, mlp, wkv, out);
}

// Round 23
// 163.134 us; speedup vs baseline: 1.5020x; 1.0069x over previous
//
#include <hip/hip_runtime.h>
#include <hip/hip_bf16.h>
#include <math.h>

typedef __attribute__((ext_vector_type(8))) short short8x;
typedef __attribute__((ext_vector_type(4))) float f32x4;
typedef __attribute__((ext_vector_type(4))) unsigned short u16x4;
typedef __attribute__((ext_vector_type(8))) unsigned short u16x8;

#define NSPLIT 16
#define NTILE 66
#define KVROWS (NTILE * 32)

__device__ __forceinline__ unsigned short f2bf(float x) {
  unsigned int u = __float_as_uint(x);
  u += 0x7fffu + ((u >> 16) & 1u);   // RNE
  return (unsigned short)(u >> 16);
}
__device__ __forceinline__ float bf2f(unsigned short u) {
  return __uint_as_float(((unsigned int)u) << 16);
}
__device__ __forceinline__ u16x4 cvt4(float4 v) {
  u16x4 r;
  r[0] = f2bf(v.x); r[1] = f2bf(v.y); r[2] = f2bf(v.z); r[3] = f2bf(v.w);
  return r;
}
__device__ __forceinline__ void gload_lds16(const void* g, void* l) {
  __builtin_amdgcn_global_load_lds(
      (const __attribute__((address_space(1))) unsigned int*)g,
      (__attribute__((address_space(3))) unsigned int*)l, 16, 0, 0);
}

// ===== kA: K-split q-proj MFMA (0..1535) || KV convert v3 (1536..3647) ========
// kPA v3: 16-row tiles staged fp32->LDS via async gload_lds (row-major linear),
// convert from LDS, fully-linear 16B stores. 4 blocks/CU.
__global__ __launch_bounds__(256, 4) void kA(
    const float* __restrict__ ckvc, const float* __restrict__ kpec,
    const float* __restrict__ ckvn, const float* __restrict__ kpein,
    const float* __restrict__ cosc, const float* __restrict__ sinc,
    const int* __restrict__ sposp, int cap,
    unsigned short* __restrict__ kvbf,
    const float* __restrict__ wq, const float* __restrict__ x,
    float* __restrict__ qpart) {
  __shared__ __align__(16) float lf[9216];   // 36,864 B (kPA half only)
  const int bx = blockIdx.x;
  const int tid = threadIdx.x;

  if (bx < 1536) {
    const int rowblock = bx >> 2, kq = bx & 3;
    const int lane = tid & 63, wid = tid >> 6;
    const int l15 = lane & 15, lg = lane >> 4;
    const int rowb = rowblock * 64 + wid * 16;
    const float* wrow = wq + (size_t)(rowb + l15) * 1536 + kq * 384 + lg * 8;
    const float* xrow = x + (size_t)l15 * 1536 + kq * 384 + lg * 8;

    f32x4 aHH = (f32x4){0.f, 0.f, 0.f, 0.f};
    f32x4 aHL = (f32x4){0.f, 0.f, 0.f, 0.f};
    f32x4 aLH = (f32x4){0.f, 0.f, 0.f, 0.f};
    f32x4 bHH = (f32x4){0.f, 0.f, 0.f, 0.f};
    f32x4 bHL = (f32x4){0.f, 0.f, 0.f, 0.f};
    f32x4 bLH = (f32x4){0.f, 0.f, 0.f, 0.f};

    float4 wA[2], wB[2], xA[2], xB[2];
#pragma unroll
    for (int i = 0; i < 2; ++i) {
      wA[i] = *(const float4*)(wrow + i * 32);
      wB[i] = *(const float4*)(wrow + i * 32 + 4);
      xA[i] = *(const float4*)(xrow + i * 32);
      xB[i] = *(const float4*)(xrow + i * 32 + 4);
    }

#pragma unroll
    for (int kc = 0; kc < 12; ++kc) {
      const int s = kc & 1;
      const float wf[8] = {wA[s].x, wA[s].y, wA[s].z, wA[s].w,
                           wB[s].x, wB[s].y, wB[s].z, wB[s].w};
      const float xf[8] = {xA[s].x, xA[s].y, xA[s].z, xA[s].w,
                           xB[s].x, xB[s].y, xB[s].z, xB[s].w};
      short8x ah, al, bh, bl;
#pragma unroll
      for (int e = 0; e < 8; ++e) {
        const unsigned int wu = __float_as_uint(wf[e]);
        const float whf = __uint_as_float(wu & 0xffff0000u);
        ah[e] = (short)(wu >> 16);
        al[e] = (short)(__float_as_uint(wf[e] - whf) >> 16);
        const unsigned int xu = __float_as_uint(xf[e]);
        const float xhf = __uint_as_float(xu & 0xffff0000u);
        bh[e] = (short)(xu >> 16);
        bl[e] = (short)(__float_as_uint(xf[e] - xhf) >> 16);
      }
      if (kc + 2 < 12) {
        wA[s] = *(const float4*)(wrow + (kc + 2) * 32);
        wB[s] = *(const float4*)(wrow + (kc + 2) * 32 + 4);
        xA[s] = *(const float4*)(xrow + (kc + 2) * 32);
        xB[s] = *(const float4*)(xrow + (kc + 2) * 32 + 4);
      }
      if (kc & 1) {
        bHH = __builtin_amdgcn_mfma_f32_16x16x32_bf16(ah, bh, bHH, 0, 0, 0);
        bHL = __builtin_amdgcn_mfma_f32_16x16x32_bf16(ah, bl, bHL, 0, 0, 0);
        bLH = __builtin_amdgcn_mfma_f32_16x16x32_bf16(al, bh, bLH, 0, 0, 0);
      } else {
        aHH = __builtin_amdgcn_mfma_f32_16x16x32_bf16(ah, bh, aHH, 0, 0, 0);
        aHL = __builtin_amdgcn_mfma_f32_16x16x32_bf16(ah, bl, aHL, 0, 0, 0);
        aLH = __builtin_amdgcn_mfma_f32_16x16x32_bf16(al, bh, aLH, 0, 0, 0);
      }
    }
    const f32x4 acc = (aHH + bHH) + (aHL + bHL) + (aLH + bLH);
#pragma unroll
    for (int r = 0; r < 4; ++r)
      qpart[(size_t)kq * 393216 + (size_t)l15 * 24576 + rowb + lg * 4 + r] = acc[r];
  } else {
    // ---- kPA v3: tile = (b, 16 rows); 1152 out-granules of 8 elems ----
    const int bxx = bx - 1536;
    const int b = bxx / 132;
    const int tile = bxx - b * 132;
    const int n0 = tile * 16;
    const int spos = sposp[0];
    unsigned short* dst = kvbf + ((size_t)b * KVROWS + n0) * 576;

    if (n0 + 15 < spos) {
      // fast: stage fp32 tile to LDS (2304 x 16B chunks, row-major linear)
      const float* cbase = ckvc + ((size_t)b * cap + n0) * 512;
      const float* pbase = kpec + ((size_t)b * cap + n0) * 64;
#pragma unroll
      for (int i = 0; i < 9; ++i) {
        const int ch = i * 256 + tid;            // 16B chunk, 144 per row
        const int row = ch / 144, cc = ch - row * 144;
        const float* s = (cc < 128) ? cbase + (size_t)row * 512 + cc * 4
                                    : pbase + (size_t)row * 64 + (cc - 128) * 4;
        gload_lds16(s, &lf[(i * 256 + (tid >> 6) * 64) * 4]);
      }
      __syncthreads();
#pragma unroll
      for (int g = 0; g < 5; ++g) {              // 1152 granules, guard
        const int u = g * 256 + tid;
        if (u < 1152) {
          const float4 a = *(const float4*)&lf[u * 8];
          const float4 c2 = *(const float4*)&lf[u * 8 + 4];
          const u16x4 lo = cvt4(a), hi = cvt4(c2);
          u16x8 w;
#pragma unroll
          for (int k = 0; k < 4; ++k) { w[k] = lo[k]; w[4 + k] = hi[k]; }
          *(u16x8*)(dst + (size_t)u * 8) = w;
        }
      }
    } else {
      // edge/tail: per-granule conditional path (1152 granules, guard)
#pragma unroll
      for (int g = 0; g < 5; ++g) {
        const int u = g * 256 + tid;
        if (u < 1152) {
          const int row = u / 72, c8 = (u - row * 72) * 8;
          const int n = n0 + row;
          u16x8 w;
          if (n > spos) {
#pragma unroll
            for (int k = 0; k < 8; ++k) w[k] = 0;
          } else if (n == spos && c8 >= 512) {
            const int d = c8 - 512;
            const float* kp = kpein + b * 64;
#pragma unroll
            for (int k = 0; k < 8; ++k) {
              const int dd = d + k;
              const int j = (dd < 32) ? dd : dd - 32;
              const float cj = cosc[spos * 64 + j], sj = sinc[spos * 64 + j];
              const float val = (dd < 32) ? kp[2 * j] * cj - kp[2 * j + 1] * sj
                                          : kp[2 * j + 1] * cj + kp[2 * j] * sj;
              w[k] = f2bf(val);
            }
          } else {
            const float* s0;
            if (n == spos) s0 = ckvn + (size_t)b * 512 + c8;
            else s0 = (c8 < 512) ? ckvc + ((size_t)b * cap + n) * 512 + c8
                                 : kpec + ((size_t)b * cap + n) * 64 + (c8 - 512);
            const u16x4 lo = cvt4(*(const float4*)s0);
            const u16x4 hi = cvt4(*(const float4*)(s0 + 4));
#pragma unroll
            for (int k = 0; k < 4; ++k) { w[k] = lo[k]; w[4 + k] = hi[k]; }
          }
          *(u16x8*)(dst + (size_t)u * 8) = w;
        }
      }
    }
  }
}

// ===== kB2: absorb (0..255) || rope (256..271) || vT build (272..1327) ========
__global__ __launch_bounds__(256) void kB2(
    const float* __restrict__ qpart, const float* __restrict__ wkv,
    const float* __restrict__ cosc, const float* __restrict__ sinc,
    const int* __restrict__ sposp, unsigned short* __restrict__ qcat,
    const unsigned short* __restrict__ kvbf, unsigned short* __restrict__ vT) {
  __shared__ __align__(16) unsigned char shbuf[36864];
  const int bx = blockIdx.x;
  const int tid = threadIdx.x;

  if (bx < 256) {
    float* qs = (float*)shbuf;   // 16*128 fp32
    const int h = bx & 127;
    const int half = bx >> 7;
    for (int u = tid; u < 2048; u += 256) {
      int bb = u >> 7, d = u & 127;
      const size_t off = (size_t)bb * 24576 + h * 192 + d;
      qs[u] = qpart[off] + qpart[off + 393216] +
              qpart[off + 786432] + qpart[off + 1179648];
    }
    __syncthreads();
    const int c = half * 256 + tid;
    float acc[16];
#pragma unroll
    for (int bb = 0; bb < 16; ++bb) acc[bb] = 0.f;
    const float* wbase = wkv + (size_t)h * 256 * 512;
    for (int d = 0; d < 128; ++d) {
      const float w = wbase[d * 512 + c];
#pragma unroll
      for (int bb = 0; bb < 16; ++bb) acc[bb] += qs[bb * 128 + d] * w;
    }
#pragma unroll
    for (int bb = 0; bb < 16; ++bb)
      qcat[(size_t)(bb * 128 + h) * 576 + c] = f2bf(acc[bb]);
  } else if (bx < 272) {
    const int b = bx - 256;
    const int pos = sposp[0];
#pragma unroll
    for (int i = 0; i < 16; ++i) {
      int idx = tid + i * 256;
      int h = idx >> 5, j = idx & 31;
      const float cj = cosc[pos * 64 + j];
      const float sj = sinc[pos * 64 + j];
      const size_t base = (size_t)b * 24576 + h * 192 + 128;
      float x0 = qpart[base + 2 * j] + qpart[base + 2 * j + 393216] +
                 qpart[base + 2 * j + 786432] + qpart[base + 2 * j + 1179648];
      float x1 = qpart[base + 2 * j + 1] + qpart[base + 2 * j + 1 + 393216] +
                 qpart[base + 2 * j + 1 + 786432] + qpart[base + 2 * j + 1 + 1179648];
      unsigned short* dst = qcat + (size_t)(b * 128 + h) * 576 + 512;
      dst[j] = f2bf(x0 * cj - x1 * sj);
      dst[j + 32] = f2bf(x1 * cj + x0 * sj);
    }
  } else {
    unsigned short* tile_sh = (unsigned short*)shbuf;  // 32*576 u16
    const int v_ = bx - 272;
    const int b = v_ / NTILE;
    const int tile = v_ - b * NTILE;
    const int wid = tid >> 6;
    const unsigned short* src = kvbf + ((size_t)b * KVROWS + tile * 32) * 576;
#pragma unroll
    for (int i = 0; i < 9; ++i) {
      const int ch = i * 256 + tid;          // 16B chunk 0..2303
      const int row = ch / 72, cc = ch - row * 72;
      gload_lds16(src + row * 576 + ((cc ^ (row & 7)) * 8),
                  &tile_sh[(i * 256 + wid * 64) * 8]);
    }
    __syncthreads();
    unsigned short* vdst = vT + ((size_t)b * NTILE + tile) * 18432;
#pragma unroll
    for (int r = 0; r < 9; ++r) {
      const int c = r * 64 + (tid >> 2);     // column 0..575
      const int q = tid & 3;                 // n-oct
      const int c8 = c >> 3, c7 = c & 7;
      u16x8 w;
#pragma unroll
      for (int j = 0; j < 8; ++j)            // element (n=q*8+j, c); n&7 == j
        w[j] = tile_sh[(q * 8 + j) * 576 + ((c8 ^ j) << 3) + c7];
      *(u16x8*)(vdst + c * 32 + q * 8) = w;
    }
  }
}

// ===== k4: flash decode, 8 waves = 128 heads, dbuf gload_lds ==================
__global__ __launch_bounds__(512, 2) void k4_attn(
    const unsigned short* __restrict__ kvbf, const unsigned short* __restrict__ vT,
    const unsigned short* __restrict__ qcat, const int* __restrict__ sposp,
    unsigned short* __restrict__ opart, float* __restrict__ mlp) {
  __shared__ __align__(16) unsigned short kv_sh[2][32 * 576];
  __shared__ __align__(16) unsigned short vt_sh[2][512 * 32];
  __shared__ __align__(16) unsigned short p_sh[8 * 640];

  const int tid = threadIdx.x;
  const int split = blockIdx.x, b = blockIdx.y;
  const int kvlen = sposp[0] + 1;
  const int lane = tid & 63, wid = tid >> 6;
  const int l15 = lane & 15, lg = lane >> 4;

  const unsigned short* kvb = kvbf + (size_t)b * KVROWS * 576;
  const unsigned short* vtb = vT + (size_t)b * NTILE * 18432;

  const int vro = lane >> 2, vq = lane & 3;
  const int vgq = vq ^ ((vro >> 1) & 3);

  auto STAGE = [&](int pb, int tt) {
    const unsigned short* ksrc = kvb + (size_t)tt * 32 * 576;
    for (int j = wid; j < 36; j += 8) {
      int u = j * 64 + lane;
      int row = u / 72, cc = u - row * 72;
      gload_lds16(ksrc + row * 576 + ((cc ^ (row & 7)) * 8), &kv_sh[pb][j * 512]);
    }
    const unsigned short* vsrc = vtb + (size_t)tt * 18432;
    for (int j = wid; j < 32; j += 8)
      gload_lds16(vsrc + j * 512 + vro * 32 + vgq * 8, &vt_sh[pb][j * 512]);
  };

  STAGE(0, split);

  const int hrow = b * 128 + wid * 16 + l15;
  const unsigned short* qrow = qcat + (size_t)hrow * 576;
  short8x qf[18];
#pragma unroll
  for (int s = 0; s < 18; ++s)
    qf[s] = *(const short8x*)(qrow + s * 32 + lg * 8);

  f32x4 acc[32];
#pragma unroll
  for (int i = 0; i < 32; ++i) acc[i] = (f32x4){0.f, 0.f, 0.f, 0.f};
  float mold[4] = {-1e30f, -1e30f, -1e30f, -1e30f};
  float lsum[4] = {0.f, 0.f, 0.f, 0.f};
  const float C2 = (1.0f / sqrtf(192.0f)) * 1.4426950408889634f;

  const int vrd = ((lg ^ ((l15 >> 1) & 3)) << 3);  // swizzled PV read chunk

  int pb = 0;
  for (int tt = split; tt * 32 < kvlen; tt += NSPLIT, pb ^= 1) {
    __syncthreads();
    if ((tt + NSPLIT) * 32 < kvlen) STAGE(pb ^ 1, tt + NSPLIT);
    const int n0 = tt * 32;

    f32x4 D0 = (f32x4){0.f, 0.f, 0.f, 0.f};
    f32x4 D1 = (f32x4){0.f, 0.f, 0.f, 0.f};
#pragma unroll
    for (int s = 0; s < 18; ++s) {
      const int c8 = (s * 4 + lg) ^ (l15 & 7);
      short8x fb0 = *(const short8x*)&kv_sh[pb][l15 * 576 + c8 * 8];
      short8x fb1 = *(const short8x*)&kv_sh[pb][(16 + l15) * 576 + c8 * 8];
      D0 = __builtin_amdgcn_mfma_f32_16x16x32_bf16(qf[s], fb0, D0, 0, 0, 0);
      D1 = __builtin_amdgcn_mfma_f32_16x16x32_bf16(qf[s], fb1, D1, 0, 0, 0);
    }

    const bool v0 = (n0 + l15) < kvlen;
    const bool v1 = (n0 + 16 + l15) < kvlen;
    float alpha[4];
#pragma unroll
    for (int r = 0; r < 4; ++r) {
      const float t0 = v0 ? D0[r] * C2 : -1e30f;
      const float t1 = v1 ? D1[r] * C2 : -1e30f;
      float mx = fmaxf(t0, t1);
      mx = fmaxf(mx, __shfl_xor(mx, 1, 64));
      mx = fmaxf(mx, __shfl_xor(mx, 2, 64));
      mx = fmaxf(mx, __shfl_xor(mx, 4, 64));
      mx = fmaxf(mx, __shfl_xor(mx, 8, 64));
      const float mn = fmaxf(mold[r], mx);
      alpha[r] = exp2f(mold[r] - mn);
      const float p0 = v0 ? exp2f(t0 - mn) : 0.f;
      const float p1 = v1 ? exp2f(t1 - mn) : 0.f;
      float rs = p0 + p1;
      rs += __shfl_xor(rs, 1, 64);
      rs += __shfl_xor(rs, 2, 64);
      rs += __shfl_xor(rs, 4, 64);
      rs += __shfl_xor(rs, 8, 64);
      lsum[r] = lsum[r] * alpha[r] + rs;
      mold[r] = mn;
      p_sh[wid * 640 + (lg * 4 + r) * 40 + l15] = f2bf(p0);
      p_sh[wid * 640 + (lg * 4 + r) * 40 + 16 + l15] = f2bf(p1);
    }
    const f32x4 av = {alpha[0], alpha[1], alpha[2], alpha[3]};
#pragma unroll
    for (int cg = 0; cg < 32; ++cg) acc[cg] *= av;

    const short8x pa = *(const short8x*)&p_sh[wid * 640 + l15 * 40 + lg * 8];
#pragma unroll
    for (int cg = 0; cg < 32; ++cg) {
      short8x bv = *(const short8x*)&vt_sh[pb][cg * 512 + l15 * 32 + vrd];
      acc[cg] = __builtin_amdgcn_mfma_f32_16x16x32_bf16(pa, bv, acc[cg], 0, 0, 0);
    }
  }

  const int hbm_ = b * 128 + wid * 16 + lg * 4;
  if (l15 == 0) {
#pragma unroll
    for (int r = 0; r < 4; ++r) {
      mlp[(size_t)(hbm_ + r) * (2 * NSPLIT) + split * 2] = mold[r];
      mlp[(size_t)(hbm_ + r) * (2 * NSPLIT) + split * 2 + 1] = lsum[r];
    }
  }

  __syncthreads();
  unsigned short* ep = &kv_sh[0][0] + wid * 8192;
#pragma unroll
  for (int cg = 0; cg < 32; ++cg)
#pragma unroll
    for (int r = 0; r < 4; ++r)
      ep[(lg * 4 + r) * 512 + cg * 16 + l15] = f2bf(acc[cg][r]);
#pragma unroll
  for (int r16 = 0; r16 < 16; ++r16) {
    const int bh = b * 128 + wid * 16 + r16;
    const size_t ob = ((size_t)bh * NSPLIT + split) * 512;
#pragma unroll
    for (int i = 0; i < 2; ++i)
      *(u16x4*)&opart[ob + i * 256 + lane * 4] =
          *(const u16x4*)&ep[r16 * 512 + i * 256 + lane * 4];
  }
}

// ===== kC: fused combine + V-proj (one block per head) ========================
__global__ __launch_bounds__(512) void kC_out(
    const unsigned short* __restrict__ opart, const float* __restrict__ mlp,
    const float* __restrict__ wkv, float* __restrict__ out) {
  __shared__ float os[16 * 512];
  __shared__ float wsc[16 * 16];
  __shared__ float lsc[16];
  const int h = blockIdx.x;
  const int tid = threadIdx.x;

  if (tid < 16) {
    const int b = tid;
    const float* m = mlp + (size_t)(b * 128 + h) * (2 * NSPLIT);
    float mi[NSPLIT], li[NSPLIT], M = -1e30f;
#pragma unroll
    for (int i = 0; i < NSPLIT; ++i) {
      mi[i] = m[i * 2];
      li[i] = m[i * 2 + 1];
      M = fmaxf(M, mi[i]);
    }
    float Ls = 0.f;
#pragma unroll
    for (int i = 0; i < NSPLIT; ++i) {
      const float w = exp2f(mi[i] - M);
      Ls += li[i] * w;
      wsc[b * NSPLIT + i] = w;
    }
    lsc[b] = Ls;
  }
  __syncthreads();

  for (int u = tid; u < 8192; u += 512) {
    const int b = u >> 9, c = u & 511;
    const unsigned short* op = opart + (size_t)(b * 128 + h) * NSPLIT * 512 + c;
    float o = 0.f;
#pragma unroll
    for (int i = 0; i < NSPLIT; ++i) o += wsc[b * NSPLIT + i] * bf2f(op[i * 512]);
    os[u] = o / lsc[b];
  }
  __syncthreads();

  const int d = tid >> 2, cq = tid & 3;
  const float* wrow = wkv + ((size_t)(h * 256 + 128 + d)) * 512;
  float acc[16];
#pragma unroll
  for (int bb = 0; bb < 16; ++bb) acc[bb] = 0.f;
  for (int i = 0; i < 32; ++i) {
    const int c = cq * 4 + i * 16;
    const float4 w4 = *(const float4*)&wrow[c];
#pragma unroll
    for (int bb = 0; bb < 16; ++bb) {
      const float4 o4 = *(const float4*)&os[bb * 512 + c];
      acc[bb] += w4.x * o4.x + w4.y * o4.y + w4.z * o4.z + w4.w * o4.w;
    }
  }
#pragma unroll
  for (int bb = 0; bb < 16; ++bb) {
    float v = acc[bb];
    v += __shfl_xor(v, 1, 64);
    v += __shfl_xor(v, 2, 64);
    if (cq == 0) out[(size_t)(bb * 128 + h) * 128 + d] = v;
  }
}

extern "C" void kernel_launch(void* const* d_in, const int* in_sizes, int n_in,
                              void* d_out, int out_size, void* d_ws, size_t ws_size,
                              hipStream_t stream) {
  const float* x = (const float*)d_in[0];
  const float* ckvn = (const float*)d_in[1];
  const float* kpein = (const float*)d_in[2];
  const int* sposp = (const int*)d_in[4];
  const float* ckvc = (const float*)d_in[5];
  const float* kpec = (const float*)d_in[6];
  const float* sinc = (const float*)d_in[7];
  const float* cosc = (const float*)d_in[8];
  const float* wkv = (const float*)d_in[9];
  const float* wq = (const float*)d_in[10];
  float* out = (float*)d_out;

  const int cap = in_sizes[5] / (16 * 512);

  float* ws = (float*)d_ws;
  float* qpart = ws;                                        // 4 x 393,216 f
  float* mlp = ws + 1572864;                                // 65,536 f
  unsigned short* qcat = (unsigned short*)(ws + 1638400);   // 1,179,648 u16
  unsigned short* kvbf = (unsigned short*)(ws + 2228224);   // 19,464,192 u16
  unsigned short* vT   = (unsigned short*)(ws + 11960320);  // 19,464,192 u16
  unsigned short* opart = (unsigned short*)(ws + 21692416); // 16,777,216 u16

  kA<<<dim3(1536 + 2112), 256, 0, stream>>>(ckvc, kpec, ckvn, kpein, cosc, sinc,
                                            sposp, cap, kvbf, wq, x, qpart);
  kB2<<<dim3(272 + NTILE * 16), 256, 0, stream>>>(qpart, wkv, cosc, sinc, sposp,
                                                  qcat, kvbf, vT);
  k4_attn<<<dim3(NSPLIT, 16), 512, 0, stream>>>(kvbf, vT, qcat, sposp, opart, mlp);
  kC_out<<<dim3(128), 512, 0, stream>>>(opart, mlp, wkv, out);
}